// Round 1
// baseline (2505.404 us; speedup 1.0000x reference)
//
#include <hip/hip_runtime.h>
#include <math.h>

#define B_ 4
#define S_ 2048
#define DIN 768
#define DOUT 768
#define H_ 12
#define DH_ 64
#define M_ (B_*S_)

// ---------------- fp32 tiled GEMM: 64x64 tile, BK=16, 256 thr, 4x4/thread ----

#define TM 64
#define TN 64
#define TKK 16

__global__ __launch_bounds__(256) void proj_gemm(
    const float* __restrict__ X,
    const float* __restrict__ Wq, const float* __restrict__ Wk, const float* __restrict__ Wv,
    float* __restrict__ Qo, float* __restrict__ Ko, float* __restrict__ Vo)
{
  __shared__ float As[TKK][TM + 4];   // As[k][m]  (A transposed in LDS)
  __shared__ float Bs[TKK][TN + 4];
  const int tid = threadIdx.x;
  const int tx = tid & 15, ty = tid >> 4;
  const int n0 = blockIdx.x * TN;
  const int m0 = blockIdx.y * TM;
  const float* W; float* Out;
  if (blockIdx.z == 0)      { W = Wq; Out = Qo; }
  else if (blockIdx.z == 1) { W = Wk; Out = Ko; }
  else                      { W = Wv; Out = Vo; }

  const int ai = tid >> 2;          // 0..63 (m within tile)
  const int ak = (tid & 3) << 2;    // 0,4,8,12 (k within tile)
  const int bk = tid >> 4;          // 0..15
  const int bj = (tid & 15) << 2;   // 0..60

  float acc[4][4] = {};
  for (int k0 = 0; k0 < DIN; k0 += TKK) {
    float4 av = *(const float4*)&X[(size_t)(m0 + ai) * DIN + k0 + ak];
    float4 bv = *(const float4*)&W[(size_t)(k0 + bk) * DOUT + n0 + bj];
    __syncthreads();
    As[ak + 0][ai] = av.x; As[ak + 1][ai] = av.y;
    As[ak + 2][ai] = av.z; As[ak + 3][ai] = av.w;
    *(float4*)&Bs[bk][bj] = bv;
    __syncthreads();
#pragma unroll
    for (int kk = 0; kk < TKK; ++kk) {
      float4 a4 = *(const float4*)&As[kk][ty << 2];
      float4 b4 = *(const float4*)&Bs[kk][tx << 2];
      float a_[4] = {a4.x, a4.y, a4.z, a4.w};
      float b_[4] = {b4.x, b4.y, b4.z, b4.w};
#pragma unroll
      for (int i = 0; i < 4; ++i)
#pragma unroll
        for (int j = 0; j < 4; ++j) acc[i][j] += a_[i] * b_[j];
    }
  }
  // store into [B, H, S, DH]; DH==TN==64 so this n-tile is exactly one head
  const int h = n0 >> 6;
#pragma unroll
  for (int i = 0; i < 4; ++i) {
    int m = m0 + (ty << 2) + i;
    int b = m >> 11, s = m & (S_ - 1);
    size_t addr = (((size_t)(b * H_ + h)) * S_ + s) * DH_ + (tx << 2);
    float4 v = make_float4(acc[i][0], acc[i][1], acc[i][2], acc[i][3]);
    *(float4*)&Out[addr] = v;
  }
}

__global__ __launch_bounds__(256) void out_gemm(
    const float* __restrict__ A, const float* __restrict__ Wo,
    const float* __restrict__ bo, float* __restrict__ Out)
{
  __shared__ float As[TKK][TM + 4];
  __shared__ float Bs[TKK][TN + 4];
  const int tid = threadIdx.x;
  const int tx = tid & 15, ty = tid >> 4;
  const int n0 = blockIdx.x * TN;
  const int m0 = blockIdx.y * TM;

  const int ai = tid >> 2;
  const int ak = (tid & 3) << 2;
  const int bk = tid >> 4;
  const int bj = (tid & 15) << 2;

  float acc[4][4] = {};
  for (int k0 = 0; k0 < DOUT; k0 += TKK) {
    float4 av = *(const float4*)&A[(size_t)(m0 + ai) * DOUT + k0 + ak];
    float4 bv = *(const float4*)&Wo[(size_t)(k0 + bk) * DOUT + n0 + bj];
    __syncthreads();
    As[ak + 0][ai] = av.x; As[ak + 1][ai] = av.y;
    As[ak + 2][ai] = av.z; As[ak + 3][ai] = av.w;
    *(float4*)&Bs[bk][bj] = bv;
    __syncthreads();
#pragma unroll
    for (int kk = 0; kk < TKK; ++kk) {
      float4 a4 = *(const float4*)&As[kk][ty << 2];
      float4 b4 = *(const float4*)&Bs[kk][tx << 2];
      float a_[4] = {a4.x, a4.y, a4.z, a4.w};
      float b_[4] = {b4.x, b4.y, b4.z, b4.w};
#pragma unroll
      for (int i = 0; i < 4; ++i)
#pragma unroll
        for (int j = 0; j < 4; ++j) acc[i][j] += a_[i] * b_[j];
    }
  }
  const int n = n0 + (tx << 2);
  float4 bias = *(const float4*)&bo[n];
#pragma unroll
  for (int i = 0; i < 4; ++i) {
    int m = m0 + (ty << 2) + i;
    float4 v = make_float4(acc[i][0] + bias.x, acc[i][1] + bias.y,
                           acc[i][2] + bias.z, acc[i][3] + bias.w);
    *(float4*)&Out[(size_t)m * DOUT + n] = v;
  }
}

// ---------------- flash attention: 1 wave per query row, 4 rows/block -------
// K staged transposed Ks[d*65+j]  -> score phase reads conflict-free
// V staged normal     Vs[j*65+d]  -> PV phase reads conflict-free

__global__ __launch_bounds__(256) void attn(
    const float* __restrict__ Q, const float* __restrict__ K,
    const float* __restrict__ V, float* __restrict__ CTX)
{
  __shared__ float Ks[64 * 65];
  __shared__ float Vs[64 * 65];
  __shared__ float Qs[4 * 64];
  __shared__ float Ps[4 * 64];

  const int tid = threadIdx.x;
  const int lane = tid & 63;
  const int wid = tid >> 6;
  const int b = blockIdx.z, h = blockIdx.y;
  const int q0 = blockIdx.x << 2;
  const int qrow = q0 + wid;
  const size_t bh = (size_t)(b * H_ + h);
  const float* Qb = Q + bh * S_ * DH_;
  const float* Kb = K + bh * S_ * DH_;
  const float* Vb = V + bh * S_ * DH_;

  // scale folded into q (softmax(scores/8) == softmax((q/8)·k))
  Qs[wid * 64 + lane] = Qb[(size_t)qrow * DH_ + lane] * 0.125f;

  float mrun = -INFINITY, lrun = 0.f, o = 0.f;
  const int ntiles = ((q0 + 3) >> 6) + 1;
  for (int t = 0; t < ntiles; ++t) {
    const int j0 = t << 6;
    __syncthreads();   // previous tile's reads done before restage
#pragma unroll 4
    for (int r = 0; r < 16; ++r) {
      int j = wid + (r << 2);
      Ks[lane * 65 + j] = Kb[(size_t)(j0 + j) * DH_ + lane];
      Vs[j * 65 + lane] = Vb[(size_t)(j0 + j) * DH_ + lane];
    }
    __syncthreads();

    // scores: lane j holds score for key j0+j
    float s = 0.f;
#pragma unroll
    for (int d = 0; d < 64; d += 4) {
      float4 qv = *(const float4*)&Qs[wid * 64 + d];   // broadcast
      s += qv.x * Ks[(d + 0) * 65 + lane];
      s += qv.y * Ks[(d + 1) * 65 + lane];
      s += qv.z * Ks[(d + 2) * 65 + lane];
      s += qv.w * Ks[(d + 3) * 65 + lane];
    }
    if (j0 + lane > qrow) s = -INFINITY;   // causal mask

    // online softmax update
    float mt = s;
#pragma unroll
    for (int off = 32; off > 0; off >>= 1) mt = fmaxf(mt, __shfl_xor(mt, off));
    float mnew = fmaxf(mrun, mt);
    float p = __expf(s - mnew);            // -inf -> 0
    float alpha = __expf(mrun - mnew);     // first tile: exp(-inf)=0
    float ps = p;
#pragma unroll
    for (int off = 32; off > 0; off >>= 1) ps += __shfl_xor(ps, off);
    lrun = lrun * alpha + ps;
    mrun = mnew;
    o *= alpha;

    Ps[wid * 64 + lane] = p;               // same-wave write->read, lgkmcnt ordered
#pragma unroll
    for (int j = 0; j < 64; j += 4) {
      float4 pv = *(const float4*)&Ps[wid * 64 + j];   // broadcast
      o += pv.x * Vs[(j + 0) * 65 + lane];
      o += pv.y * Vs[(j + 1) * 65 + lane];
      o += pv.z * Vs[(j + 2) * 65 + lane];
      o += pv.w * Vs[(j + 3) * 65 + lane];
    }
  }
  // CTX laid out [B*S, DOUT] for the output GEMM
  CTX[((size_t)(b * S_ + qrow)) * DOUT + h * DH_ + lane] = o / lrun;
}

// ---------------- launcher ----------------

extern "C" void kernel_launch(void* const* d_in, const int* in_sizes, int n_in,
                              void* d_out, int out_size, void* d_ws, size_t ws_size,
                              hipStream_t stream) {
  const float* X  = (const float*)d_in[0];
  // d_in[1] is the causal mask (bool) — it is exactly triu(k=1), hardcoded.
  const float* Wq = (const float*)d_in[2];
  const float* Wk = (const float*)d_in[3];
  const float* Wv = (const float*)d_in[4];
  const float* Wo = (const float*)d_in[5];
  const float* bo = (const float*)d_in[6];
  float* out = (float*)d_out;

  float* Qw  = (float*)d_ws;                       // [B,H,S,DH]
  float* Kw  = Qw + (size_t)M_ * DOUT;
  float* Vw  = Kw + (size_t)M_ * DOUT;
  float* CTX = Vw + (size_t)M_ * DOUT;             // [M, DOUT]

  proj_gemm<<<dim3(DOUT / TN, M_ / TM, 3), 256, 0, stream>>>(X, Wq, Wk, Wv, Qw, Kw, Vw);
  attn<<<dim3(S_ / 4, H_, B_), 256, 0, stream>>>(Qw, Kw, Vw, CTX);
  out_gemm<<<dim3(DOUT / TN, M_ / TM), 256, 0, stream>>>(CTX, Wo, bo, out);
}

// Round 2
// 836.102 us; speedup vs baseline: 2.9965x; 2.9965x over previous
//
#include <hip/hip_runtime.h>
#include <math.h>

typedef __attribute__((ext_vector_type(4))) float f32x4;
typedef __attribute__((ext_vector_type(8))) short s16x8;

#define B_ 4
#define S_ 2048
#define DIN 768
#define DOUT 768
#define H_ 12
#define DH_ 64
#define M_ (B_*S_)

__device__ __forceinline__ unsigned short f2bf(float f) {
  union { float f; unsigned u; } v; v.f = f;
  unsigned r = v.u + 0x7fffu + ((v.u >> 16) & 1u);
  return (unsigned short)(r >> 16);
}

// ---------------- fp32 tiled GEMM: 64x64 tile, BK=16, 256 thr, 4x4/thread ----
// Emits bf16 Q (pre-scaled by 1/sqrt(DH)), K, V in [B,H,S,DH].

#define TM 64
#define TN 64
#define TKK 16

__global__ __launch_bounds__(256) void proj_gemm(
    const float* __restrict__ X,
    const float* __restrict__ Wq, const float* __restrict__ Wk, const float* __restrict__ Wv,
    unsigned short* __restrict__ Qo, unsigned short* __restrict__ Ko,
    unsigned short* __restrict__ Vo)
{
  __shared__ float As[TKK][TM + 4];   // As[k][m]  (A transposed in LDS)
  __shared__ float Bs[TKK][TN + 4];
  const int tid = threadIdx.x;
  const int tx = tid & 15, ty = tid >> 4;
  const int n0 = blockIdx.x * TN;
  const int m0 = blockIdx.y * TM;
  const float* W; unsigned short* Out; float scale;
  if (blockIdx.z == 0)      { W = Wq; Out = Qo; scale = 0.125f; }
  else if (blockIdx.z == 1) { W = Wk; Out = Ko; scale = 1.0f; }
  else                      { W = Wv; Out = Vo; scale = 1.0f; }

  const int ai = tid >> 2;          // 0..63 (m within tile)
  const int ak = (tid & 3) << 2;    // 0,4,8,12 (k within tile)
  const int bk = tid >> 4;          // 0..15
  const int bj = (tid & 15) << 2;   // 0..60

  float acc[4][4] = {};
  for (int k0 = 0; k0 < DIN; k0 += TKK) {
    float4 av = *(const float4*)&X[(size_t)(m0 + ai) * DIN + k0 + ak];
    float4 bv = *(const float4*)&W[(size_t)(k0 + bk) * DOUT + n0 + bj];
    __syncthreads();
    As[ak + 0][ai] = av.x; As[ak + 1][ai] = av.y;
    As[ak + 2][ai] = av.z; As[ak + 3][ai] = av.w;
    *(float4*)&Bs[bk][bj] = bv;
    __syncthreads();
#pragma unroll
    for (int kk = 0; kk < TKK; ++kk) {
      float4 a4 = *(const float4*)&As[kk][ty << 2];
      float4 b4 = *(const float4*)&Bs[kk][tx << 2];
      float a_[4] = {a4.x, a4.y, a4.z, a4.w};
      float b_[4] = {b4.x, b4.y, b4.z, b4.w};
#pragma unroll
      for (int i = 0; i < 4; ++i)
#pragma unroll
        for (int j = 0; j < 4; ++j) acc[i][j] += a_[i] * b_[j];
    }
  }
  // store bf16 into [B, H, S, DH]; DH==TN==64 so this n-tile is exactly one head
  const int h = n0 >> 6;
#pragma unroll
  for (int i = 0; i < 4; ++i) {
    int m = m0 + (ty << 2) + i;
    int b = m >> 11, s = m & (S_ - 1);
    size_t addr = (((size_t)(b * H_ + h)) * S_ + s) * DH_ + (tx << 2);
    ushort4 v;
    v.x = f2bf(acc[i][0] * scale); v.y = f2bf(acc[i][1] * scale);
    v.z = f2bf(acc[i][2] * scale); v.w = f2bf(acc[i][3] * scale);
    *(ushort4*)&Out[addr] = v;
  }
}

__global__ __launch_bounds__(256) void out_gemm(
    const float* __restrict__ A, const float* __restrict__ Wo,
    const float* __restrict__ bo, float* __restrict__ Out)
{
  __shared__ float As[TKK][TM + 4];
  __shared__ float Bs[TKK][TN + 4];
  const int tid = threadIdx.x;
  const int tx = tid & 15, ty = tid >> 4;
  const int n0 = blockIdx.x * TN;
  const int m0 = blockIdx.y * TM;

  const int ai = tid >> 2;
  const int ak = (tid & 3) << 2;
  const int bk = tid >> 4;
  const int bj = (tid & 15) << 2;

  float acc[4][4] = {};
  for (int k0 = 0; k0 < DOUT; k0 += TKK) {
    float4 av = *(const float4*)&A[(size_t)(m0 + ai) * DOUT + k0 + ak];
    float4 bv = *(const float4*)&Wo[(size_t)(k0 + bk) * DOUT + n0 + bj];
    __syncthreads();
    As[ak + 0][ai] = av.x; As[ak + 1][ai] = av.y;
    As[ak + 2][ai] = av.z; As[ak + 3][ai] = av.w;
    *(float4*)&Bs[bk][bj] = bv;
    __syncthreads();
#pragma unroll
    for (int kk = 0; kk < TKK; ++kk) {
      float4 a4 = *(const float4*)&As[kk][ty << 2];
      float4 b4 = *(const float4*)&Bs[kk][tx << 2];
      float a_[4] = {a4.x, a4.y, a4.z, a4.w};
      float b_[4] = {b4.x, b4.y, b4.z, b4.w};
#pragma unroll
      for (int i = 0; i < 4; ++i)
#pragma unroll
        for (int j = 0; j < 4; ++j) acc[i][j] += a_[i] * b_[j];
    }
  }
  const int n = n0 + (tx << 2);
  float4 bias = *(const float4*)&bo[n];
#pragma unroll
  for (int i = 0; i < 4; ++i) {
    int m = m0 + (ty << 2) + i;
    float4 v = make_float4(acc[i][0] + bias.x, acc[i][1] + bias.y,
                           acc[i][2] + bias.z, acc[i][3] + bias.w);
    *(float4*)&Out[(size_t)m * DOUT + n] = v;
  }
}

// ---------------- MFMA flash attention ------------------------------------
// Block = 64 query rows (4 waves x 16 rows), K-tiles of 64 keys.
// Q/K fragments: direct 16B global loads (A/B layout: lane&15 = m/n,
// k = (lane>>4)*8 + j). V staged transposed in LDS (Vt[d][key], stride 72
// ushorts => +4-bank row rotation, conflict-free ds_read_b128). P transits
// LDS to convert C-layout -> A-layout (m120-verified pattern).

#define PSTR 72

__global__ __launch_bounds__(256) void attn_mfma(
    const unsigned short* __restrict__ Q, const unsigned short* __restrict__ K,
    const unsigned short* __restrict__ V, float* __restrict__ CTX)
{
  __shared__ unsigned short Vt[64 * PSTR];       // 9 KB
  __shared__ unsigned short Ps[4 * 16 * PSTR];   // 9 KB

  const int tid = threadIdx.x;
  const int lane = tid & 63;
  const int w = tid >> 6;
  const int col_l = lane & 15;
  const int quad = lane >> 4;
  const int b = blockIdx.z, h = blockIdx.y;
  const int qtile = gridDim.x - 1 - blockIdx.x;  // longest blocks first
  const int q0 = qtile << 6;
  const int qw0 = q0 + (w << 4);
  const size_t bh = (size_t)(b * H_ + h);
  const unsigned short* Qb = Q + bh * S_ * DH_;
  const unsigned short* Kb = K + bh * S_ * DH_;
  const unsigned short* Vb = V + bh * S_ * DH_;

  // Q fragments for this wave's 16 rows (scale folded in at projection)
  s16x8 aq0 = *(const s16x8*)&Qb[(size_t)(qw0 + col_l) * DH_ + quad * 8];
  s16x8 aq1 = *(const s16x8*)&Qb[(size_t)(qw0 + col_l) * DH_ + 32 + quad * 8];

  f32x4 oacc[4] = {};
  float mrun[4], lrun[4];
#pragma unroll
  for (int r = 0; r < 4; ++r) { mrun[r] = -INFINITY; lrun[r] = 0.f; }

  const int vkey = tid & 63;
  const int ntiles = qtile + 1;
  for (int t = 0; t < ntiles; ++t) {
    const int j0 = t << 6;
    __syncthreads();                 // prior tile's Vt reads done
    // stage V transposed: Vt[d][key]
#pragma unroll
    for (int it = 0; it < 2; ++it) {
      int chunk = (tid >> 6) + (it << 2);        // 0..7
      s16x8 vv = *(const s16x8*)&Vb[(size_t)(j0 + vkey) * DH_ + chunk * 8];
#pragma unroll
      for (int j = 0; j < 8; ++j)
        Vt[(chunk * 8 + j) * PSTR + vkey] = (unsigned short)vv[j];
    }
    // K fragments (issue early, overlap with staging)
    s16x8 kf[4][2];
#pragma unroll
    for (int nc = 0; nc < 4; ++nc) {
      const unsigned short* kr = &Kb[(size_t)(j0 + nc * 16 + col_l) * DH_ + quad * 8];
      kf[nc][0] = *(const s16x8*)kr;
      kf[nc][1] = *(const s16x8*)(kr + 32);
    }
    __syncthreads();

    // scores: sc[nc] reg r = S[row=qw0+quad*4+r][col=j0+nc*16+col_l]
    f32x4 sc[4];
#pragma unroll
    for (int nc = 0; nc < 4; ++nc) {
      f32x4 a = {};
      a = __builtin_amdgcn_mfma_f32_16x16x32_bf16(aq0, kf[nc][0], a, 0, 0, 0);
      a = __builtin_amdgcn_mfma_f32_16x16x32_bf16(aq1, kf[nc][1], a, 0, 0, 0);
      sc[nc] = a;
    }
    if (j0 == q0) {                  // causal mask, diagonal tile only
#pragma unroll
      for (int nc = 0; nc < 4; ++nc)
#pragma unroll
        for (int r = 0; r < 4; ++r)
          if (j0 + nc * 16 + col_l > qw0 + quad * 4 + r) sc[nc][r] = -INFINITY;
    }

    // online softmax (rows live across the 16 lanes of each quad)
    float pr[4][4];
#pragma unroll
    for (int r = 0; r < 4; ++r) {
      float m = fmaxf(fmaxf(sc[0][r], sc[1][r]), fmaxf(sc[2][r], sc[3][r]));
      m = fmaxf(m, __shfl_xor(m, 1));
      m = fmaxf(m, __shfl_xor(m, 2));
      m = fmaxf(m, __shfl_xor(m, 4));
      m = fmaxf(m, __shfl_xor(m, 8));
      float mnew = fmaxf(mrun[r], m);
      float alpha = __expf(mrun[r] - mnew);      // first tile: exp(-inf)=0
      float ps = 0.f;
#pragma unroll
      for (int nc = 0; nc < 4; ++nc) {
        float p = __expf(sc[nc][r] - mnew);      // masked: exp(-inf)=0
        pr[nc][r] = p;
        ps += p;
      }
      ps += __shfl_xor(ps, 1);
      ps += __shfl_xor(ps, 2);
      ps += __shfl_xor(ps, 4);
      ps += __shfl_xor(ps, 8);
      lrun[r] = lrun[r] * alpha + ps;
      mrun[r] = mnew;
#pragma unroll
      for (int dc = 0; dc < 4; ++dc) oacc[dc][r] *= alpha;
    }

    // P -> LDS (wave-private region; DS ops are in-order within a wave)
#pragma unroll
    for (int nc = 0; nc < 4; ++nc)
#pragma unroll
      for (int r = 0; r < 4; ++r)
        Ps[(w * 16 + quad * 4 + r) * PSTR + nc * 16 + col_l] = f2bf(pr[nc][r]);

    // PV: A = P (from LDS, A-layout), B = V^T (from Vt)
    s16x8 ap0 = *(const s16x8*)&Ps[(w * 16 + col_l) * PSTR + quad * 8];
    s16x8 ap1 = *(const s16x8*)&Ps[(w * 16 + col_l) * PSTR + 32 + quad * 8];
#pragma unroll
    for (int dc = 0; dc < 4; ++dc) {
      s16x8 bv0 = *(const s16x8*)&Vt[(dc * 16 + col_l) * PSTR + quad * 8];
      s16x8 bv1 = *(const s16x8*)&Vt[(dc * 16 + col_l) * PSTR + 32 + quad * 8];
      oacc[dc] = __builtin_amdgcn_mfma_f32_16x16x32_bf16(ap0, bv0, oacc[dc], 0, 0, 0);
      oacc[dc] = __builtin_amdgcn_mfma_f32_16x16x32_bf16(ap1, bv1, oacc[dc], 0, 0, 0);
    }
  }

  // epilogue: CTX[b*S+q][h*64+d] = O/l
  float rinv[4];
#pragma unroll
  for (int r = 0; r < 4; ++r) rinv[r] = 1.0f / lrun[r];
#pragma unroll
  for (int dc = 0; dc < 4; ++dc)
#pragma unroll
    for (int r = 0; r < 4; ++r)
      CTX[((size_t)(b * S_ + qw0 + quad * 4 + r)) * DOUT + h * DH_ + dc * 16 + col_l]
          = oacc[dc][r] * rinv[r];
}

// ---------------- launcher ----------------

extern "C" void kernel_launch(void* const* d_in, const int* in_sizes, int n_in,
                              void* d_out, int out_size, void* d_ws, size_t ws_size,
                              hipStream_t stream) {
  const float* X  = (const float*)d_in[0];
  // d_in[1] is the causal mask (bool) — exactly triu(k=1), hardcoded in attn.
  const float* Wq = (const float*)d_in[2];
  const float* Wk = (const float*)d_in[3];
  const float* Wv = (const float*)d_in[4];
  const float* Wo = (const float*)d_in[5];
  const float* bo = (const float*)d_in[6];
  float* out = (float*)d_out;

  float* CTX = (float*)d_ws;                          // [M, DOUT] fp32, 25 MB
  unsigned short* Qb = (unsigned short*)(CTX + (size_t)M_ * DOUT);  // bf16 [B,H,S,DH]
  unsigned short* Kb = Qb + (size_t)M_ * DOUT;
  unsigned short* Vb = Kb + (size_t)M_ * DOUT;

  proj_gemm<<<dim3(DOUT / TN, M_ / TM, 3), 256, 0, stream>>>(X, Wq, Wk, Wv, Qb, Kb, Vb);
  attn_mfma<<<dim3(S_ / 64, H_, B_), 256, 0, stream>>>(Qb, Kb, Vb, CTX);
  out_gemm<<<dim3(DOUT / TN, M_ / TM), 256, 0, stream>>>(CTX, Wo, bo, out);
}

// Round 3
// 393.640 us; speedup vs baseline: 6.3647x; 2.1240x over previous
//
#include <hip/hip_runtime.h>
#include <math.h>

typedef __attribute__((ext_vector_type(4))) float f32x4;
typedef __attribute__((ext_vector_type(8))) short s16x8;
typedef __attribute__((ext_vector_type(8))) unsigned short u16x8;

#define B_ 4
#define S_ 2048
#define DIN 768
#define DOUT 768
#define H_ 12
#define DH_ 64
#define M_ (B_*S_)

__device__ __forceinline__ unsigned short f2bf(float f) {
  union { float f; unsigned u; } v; v.f = f;
  unsigned r = v.u + 0x7fffu + ((v.u >> 16) & 1u);
  return (unsigned short)(r >> 16);
}

// ---------------- prep: casts -----------------------------------------------

__global__ __launch_bounds__(256) void cast_x(const float* __restrict__ X,
                                              unsigned short* __restrict__ Xb) {
  size_t i = ((size_t)blockIdx.x * 256 + threadIdx.x) * 8;
  float4 a = *(const float4*)&X[i];
  float4 b = *(const float4*)&X[i + 4];
  u16x8 v;
  v[0] = f2bf(a.x); v[1] = f2bf(a.y); v[2] = f2bf(a.z); v[3] = f2bf(a.w);
  v[4] = f2bf(b.x); v[5] = f2bf(b.y); v[6] = f2bf(b.z); v[7] = f2bf(b.w);
  *(u16x8*)&Xb[i] = v;
}

// transpose-cast: W[k][n] fp32 -> Wt[n][k] bf16 (z selects among 4 weights)
__global__ __launch_bounds__(256) void tcast_w(
    const float* __restrict__ W0, const float* __restrict__ W1,
    const float* __restrict__ W2, const float* __restrict__ W3,
    unsigned short* __restrict__ Wt) {
  __shared__ float t[32][33];
  const float* W = blockIdx.z == 0 ? W0 : blockIdx.z == 1 ? W1
                 : blockIdx.z == 2 ? W2 : W3;
  unsigned short* Out = Wt + (size_t)blockIdx.z * DOUT * DIN;
  const int n0 = blockIdx.x * 32, k0 = blockIdx.y * 32;
  const int tx = threadIdx.x & 31, ty = threadIdx.x >> 5;  // 8 rows/pass
#pragma unroll
  for (int i = 0; i < 32; i += 8)
    t[ty + i][tx] = W[(size_t)(k0 + ty + i) * DOUT + n0 + tx];
  __syncthreads();
#pragma unroll
  for (int i = 0; i < 32; i += 8)
    Out[(size_t)(n0 + ty + i) * DIN + k0 + tx] = f2bf(t[tx][ty + i]);
}

// ---------------- bf16 MFMA GEMM core (m97 structure) -----------------------
// 128x128 tile, BK=32, 4 waves x (4x4) 16x16x32 MFMA.
// global_load_lds width=16 staging with XOR chunk swizzle (row>>1)&3 so
// fragment ds_read_b128s are 2-way (free) instead of 8-way conflicted.

#define BKC 32   // bf16 elements per K step

__device__ __forceinline__ void stage_tile(
    const unsigned short* __restrict__ g, int row0, int k0,
    unsigned short* lds, int tid)
{
#pragma unroll
  for (int it = 0; it < 2; ++it) {
    int s = it * 256 + tid;              // chunk id 0..511 (16B chunks)
    int row = s >> 2, sc = s & 3;
    int gc = sc ^ ((row >> 1) & 3);      // swizzled source chunk
    const unsigned short* gsrc = g + (size_t)(row0 + row) * 768 + k0 + gc * 8;
    unsigned short* dst = lds + (size_t)(it * 256 + (tid & ~63)) * 8; // wave-uniform
    __builtin_amdgcn_global_load_lds(
        (const __attribute__((address_space(1))) void*)gsrc,
        (__attribute__((address_space(3))) void*)dst, 16, 0, 0);
  }
}

__device__ __forceinline__ void gemm_core(
    const unsigned short* __restrict__ A, const unsigned short* __restrict__ Bt,
    int m0, int n0, unsigned short* As, unsigned short* Bs,
    f32x4 acc[4][4], int tid)
{
  const int lane = tid & 63;
  const int col_l = lane & 15, quad = lane >> 4;
  const int w = tid >> 6;
  const int wm = (w & 1) * 64, wn = (w >> 1) * 64;
  for (int k0 = 0; k0 < 768; k0 += BKC) {
    __syncthreads();
    stage_tile(A, m0, k0, As, tid);
    stage_tile(Bt, n0, k0, Bs, tid);
    __syncthreads();
    s16x8 af[4], bf[4];
#pragma unroll
    for (int t = 0; t < 4; ++t) {
      int ar = wm + t * 16 + col_l;
      af[t] = *(const s16x8*)&As[ar * 32 + (quad ^ ((ar >> 1) & 3)) * 8];
      int br = wn + t * 16 + col_l;
      bf[t] = *(const s16x8*)&Bs[br * 32 + (quad ^ ((br >> 1) & 3)) * 8];
    }
#pragma unroll
    for (int mt = 0; mt < 4; ++mt)
#pragma unroll
      for (int nt = 0; nt < 4; ++nt)
        acc[mt][nt] = __builtin_amdgcn_mfma_f32_16x16x32_bf16(
            af[mt], bf[nt], acc[mt][nt], 0, 0, 0);
  }
}

// X@W -> Q/K/V bf16 [B,H,S,DH]; Q pre-scaled by 1/8
__global__ __launch_bounds__(256) void proj_mfma(
    const unsigned short* __restrict__ Xb, const unsigned short* __restrict__ Wt,
    unsigned short* __restrict__ Qo, unsigned short* __restrict__ Ko,
    unsigned short* __restrict__ Vo)
{
  __shared__ unsigned short As[128 * 32];
  __shared__ unsigned short Bs[128 * 32];
  const int tid = threadIdx.x;
  const int m0 = blockIdx.y * 128, n0 = blockIdx.x * 128;
  const int z = blockIdx.z;
  const unsigned short* Bw = Wt + (size_t)z * DOUT * DIN;
  unsigned short* Out = z == 0 ? Qo : z == 1 ? Ko : Vo;
  const float scale = z == 0 ? 0.125f : 1.0f;

  f32x4 acc[4][4] = {};
  gemm_core(Xb, Bw, m0, n0, As, Bs, acc, tid);

  const int lane = tid & 63, w = tid >> 6;
  const int col_l = lane & 15, quad = lane >> 4;
  const int wm = (w & 1) * 64, wn = (w >> 1) * 64;
#pragma unroll
  for (int mt = 0; mt < 4; ++mt)
#pragma unroll
    for (int nt = 0; nt < 4; ++nt) {
      int n = n0 + wn + nt * 16 + col_l;
      int h = n >> 6, d = n & 63;
#pragma unroll
      for (int r = 0; r < 4; ++r) {
        int m = m0 + wm + mt * 16 + quad * 4 + r;
        int b = m >> 11, s = m & (S_ - 1);
        Out[(((size_t)(b * H_ + h)) * S_ + s) * DH_ + d] = f2bf(acc[mt][nt][r] * scale);
      }
    }
}

// CTX@Wo + bo -> out fp32 [M, DOUT]
__global__ __launch_bounds__(256) void out_mfma(
    const unsigned short* __restrict__ Cb, const unsigned short* __restrict__ Wt,
    const float* __restrict__ bo, float* __restrict__ Out)
{
  __shared__ unsigned short As[128 * 32];
  __shared__ unsigned short Bs[128 * 32];
  const int tid = threadIdx.x;
  const int m0 = blockIdx.y * 128, n0 = blockIdx.x * 128;

  f32x4 acc[4][4] = {};
  gemm_core(Cb, Wt, m0, n0, As, Bs, acc, tid);

  const int lane = tid & 63, w = tid >> 6;
  const int col_l = lane & 15, quad = lane >> 4;
  const int wm = (w & 1) * 64, wn = (w >> 1) * 64;
#pragma unroll
  for (int mt = 0; mt < 4; ++mt)
#pragma unroll
    for (int nt = 0; nt < 4; ++nt) {
      int n = n0 + wn + nt * 16 + col_l;
      float bias = bo[n];
#pragma unroll
      for (int r = 0; r < 4; ++r) {
        int m = m0 + wm + mt * 16 + quad * 4 + r;
        Out[(size_t)m * DOUT + n] = acc[mt][nt][r] + bias;
      }
    }
}

// ---------------- MFMA flash attention (unchanged except bf16 CTX) ---------

#define PSTR 72

__global__ __launch_bounds__(256) void attn_mfma(
    const unsigned short* __restrict__ Q, const unsigned short* __restrict__ K,
    const unsigned short* __restrict__ V, unsigned short* __restrict__ CTX)
{
  __shared__ unsigned short Vt[64 * PSTR];
  __shared__ unsigned short Ps[4 * 16 * PSTR];

  const int tid = threadIdx.x;
  const int lane = tid & 63;
  const int w = tid >> 6;
  const int col_l = lane & 15;
  const int quad = lane >> 4;
  const int b = blockIdx.z, h = blockIdx.y;
  const int qtile = gridDim.x - 1 - blockIdx.x;  // longest blocks first
  const int q0 = qtile << 6;
  const int qw0 = q0 + (w << 4);
  const size_t bh = (size_t)(b * H_ + h);
  const unsigned short* Qb = Q + bh * S_ * DH_;
  const unsigned short* Kb = K + bh * S_ * DH_;
  const unsigned short* Vb = V + bh * S_ * DH_;

  s16x8 aq0 = *(const s16x8*)&Qb[(size_t)(qw0 + col_l) * DH_ + quad * 8];
  s16x8 aq1 = *(const s16x8*)&Qb[(size_t)(qw0 + col_l) * DH_ + 32 + quad * 8];

  f32x4 oacc[4] = {};
  float mrun[4], lrun[4];
#pragma unroll
  for (int r = 0; r < 4; ++r) { mrun[r] = -INFINITY; lrun[r] = 0.f; }

  const int vkey = tid & 63;
  const int ntiles = qtile + 1;
  for (int t = 0; t < ntiles; ++t) {
    const int j0 = t << 6;
    __syncthreads();
#pragma unroll
    for (int it = 0; it < 2; ++it) {
      int chunk = (tid >> 6) + (it << 2);
      s16x8 vv = *(const s16x8*)&Vb[(size_t)(j0 + vkey) * DH_ + chunk * 8];
#pragma unroll
      for (int j = 0; j < 8; ++j)
        Vt[(chunk * 8 + j) * PSTR + vkey] = (unsigned short)vv[j];
    }
    s16x8 kf[4][2];
#pragma unroll
    for (int nc = 0; nc < 4; ++nc) {
      const unsigned short* kr = &Kb[(size_t)(j0 + nc * 16 + col_l) * DH_ + quad * 8];
      kf[nc][0] = *(const s16x8*)kr;
      kf[nc][1] = *(const s16x8*)(kr + 32);
    }
    __syncthreads();

    f32x4 sc[4];
#pragma unroll
    for (int nc = 0; nc < 4; ++nc) {
      f32x4 a = {};
      a = __builtin_amdgcn_mfma_f32_16x16x32_bf16(aq0, kf[nc][0], a, 0, 0, 0);
      a = __builtin_amdgcn_mfma_f32_16x16x32_bf16(aq1, kf[nc][1], a, 0, 0, 0);
      sc[nc] = a;
    }
    if (j0 == q0) {
#pragma unroll
      for (int nc = 0; nc < 4; ++nc)
#pragma unroll
        for (int r = 0; r < 4; ++r)
          if (j0 + nc * 16 + col_l > qw0 + quad * 4 + r) sc[nc][r] = -INFINITY;
    }

    float pr[4][4];
#pragma unroll
    for (int r = 0; r < 4; ++r) {
      float m = fmaxf(fmaxf(sc[0][r], sc[1][r]), fmaxf(sc[2][r], sc[3][r]));
      m = fmaxf(m, __shfl_xor(m, 1));
      m = fmaxf(m, __shfl_xor(m, 2));
      m = fmaxf(m, __shfl_xor(m, 4));
      m = fmaxf(m, __shfl_xor(m, 8));
      float mnew = fmaxf(mrun[r], m);
      float alpha = __expf(mrun[r] - mnew);
      float ps = 0.f;
#pragma unroll
      for (int nc = 0; nc < 4; ++nc) {
        float p = __expf(sc[nc][r] - mnew);
        pr[nc][r] = p;
        ps += p;
      }
      ps += __shfl_xor(ps, 1);
      ps += __shfl_xor(ps, 2);
      ps += __shfl_xor(ps, 4);
      ps += __shfl_xor(ps, 8);
      lrun[r] = lrun[r] * alpha + ps;
      mrun[r] = mnew;
#pragma unroll
      for (int dc = 0; dc < 4; ++dc) oacc[dc][r] *= alpha;
    }

#pragma unroll
    for (int nc = 0; nc < 4; ++nc)
#pragma unroll
      for (int r = 0; r < 4; ++r)
        Ps[(w * 16 + quad * 4 + r) * PSTR + nc * 16 + col_l] = f2bf(pr[nc][r]);

    s16x8 ap0 = *(const s16x8*)&Ps[(w * 16 + col_l) * PSTR + quad * 8];
    s16x8 ap1 = *(const s16x8*)&Ps[(w * 16 + col_l) * PSTR + 32 + quad * 8];
#pragma unroll
    for (int dc = 0; dc < 4; ++dc) {
      s16x8 bv0 = *(const s16x8*)&Vt[(dc * 16 + col_l) * PSTR + quad * 8];
      s16x8 bv1 = *(const s16x8*)&Vt[(dc * 16 + col_l) * PSTR + 32 + quad * 8];
      oacc[dc] = __builtin_amdgcn_mfma_f32_16x16x32_bf16(ap0, bv0, oacc[dc], 0, 0, 0);
      oacc[dc] = __builtin_amdgcn_mfma_f32_16x16x32_bf16(ap1, bv1, oacc[dc], 0, 0, 0);
    }
  }

  float rinv[4];
#pragma unroll
  for (int r = 0; r < 4; ++r) rinv[r] = 1.0f / lrun[r];
#pragma unroll
  for (int dc = 0; dc < 4; ++dc)
#pragma unroll
    for (int r = 0; r < 4; ++r)
      CTX[((size_t)(b * S_ + qw0 + quad * 4 + r)) * DOUT + h * DH_ + dc * 16 + col_l]
          = f2bf(oacc[dc][r] * rinv[r]);
}

// ---------------- launcher ----------------

extern "C" void kernel_launch(void* const* d_in, const int* in_sizes, int n_in,
                              void* d_out, int out_size, void* d_ws, size_t ws_size,
                              hipStream_t stream) {
  const float* X  = (const float*)d_in[0];
  // d_in[1] is the causal mask (bool) — exactly triu(k=1), hardcoded in attn.
  const float* Wq = (const float*)d_in[2];
  const float* Wk = (const float*)d_in[3];
  const float* Wv = (const float*)d_in[4];
  const float* Wo = (const float*)d_in[5];
  const float* bo = (const float*)d_in[6];
  float* out = (float*)d_out;

  unsigned short* Xb = (unsigned short*)d_ws;            // [M, DIN] bf16
  unsigned short* Wt = Xb + (size_t)M_ * DIN;            // [4][DOUT][DIN] bf16 (n-major)
  unsigned short* Qb = Wt + (size_t)4 * DOUT * DIN;      // [B,H,S,DH] bf16
  unsigned short* Kb = Qb + (size_t)M_ * DOUT;
  unsigned short* Vb = Kb + (size_t)M_ * DOUT;
  unsigned short* Cb = Vb + (size_t)M_ * DOUT;           // [M, DOUT] bf16

  cast_x<<<dim3((M_ * DIN) / (256 * 8)), 256, 0, stream>>>(X, Xb);
  tcast_w<<<dim3(DOUT / 32, DIN / 32, 4), 256, 0, stream>>>(Wq, Wk, Wv, Wo, Wt);
  proj_mfma<<<dim3(DOUT / 128, M_ / 128, 3), 256, 0, stream>>>(Xb, Wt, Qb, Kb, Vb);
  attn_mfma<<<dim3(S_ / 64, H_, B_), 256, 0, stream>>>(Qb, Kb, Vb, Cb);
  out_mfma<<<dim3(DOUT / 128, M_ / 128), 256, 0, stream>>>(
      Cb, Wt + (size_t)3 * DOUT * DIN, bo, out);
}

// Round 4
// 243.579 us; speedup vs baseline: 10.2858x; 1.6161x over previous
//
#include <hip/hip_runtime.h>
#include <hip/hip_bf16.h>
#include <math.h>

typedef __attribute__((ext_vector_type(4))) float f32x4;
typedef __attribute__((ext_vector_type(8))) short s16x8;
typedef __attribute__((ext_vector_type(8))) unsigned short u16x8;

#define B_ 4
#define S_ 2048
#define DIN 768
#define DOUT 768
#define H_ 12
#define DH_ 64
#define M_ (B_*S_)

__device__ __forceinline__ unsigned short f2bf(float f) {
  union { float f; unsigned u; } v; v.f = f;
  unsigned r = v.u + 0x7fffu + ((v.u >> 16) & 1u);
  return (unsigned short)(r >> 16);
}

// ---------------- prep: casts -----------------------------------------------

__global__ __launch_bounds__(256) void cast_x(const float* __restrict__ X,
                                              unsigned short* __restrict__ Xb) {
  size_t i = ((size_t)blockIdx.x * 256 + threadIdx.x) * 8;
  float4 a = *(const float4*)&X[i];
  float4 b = *(const float4*)&X[i + 4];
  u16x8 v;
  v[0] = f2bf(a.x); v[1] = f2bf(a.y); v[2] = f2bf(a.z); v[3] = f2bf(a.w);
  v[4] = f2bf(b.x); v[5] = f2bf(b.y); v[6] = f2bf(b.z); v[7] = f2bf(b.w);
  *(u16x8*)&Xb[i] = v;
}

// transpose-cast: W[k][n] fp32 -> Wt[n][k] bf16 (z selects among 4 weights)
__global__ __launch_bounds__(256) void tcast_w(
    const float* __restrict__ W0, const float* __restrict__ W1,
    const float* __restrict__ W2, const float* __restrict__ W3,
    unsigned short* __restrict__ Wt) {
  __shared__ float t[32][33];
  const float* W = blockIdx.z == 0 ? W0 : blockIdx.z == 1 ? W1
                 : blockIdx.z == 2 ? W2 : W3;
  unsigned short* Out = Wt + (size_t)blockIdx.z * DOUT * DIN;
  const int n0 = blockIdx.x * 32, k0 = blockIdx.y * 32;
  const int tx = threadIdx.x & 31, ty = threadIdx.x >> 5;  // 8 rows/pass
#pragma unroll
  for (int i = 0; i < 32; i += 8)
    t[ty + i][tx] = W[(size_t)(k0 + ty + i) * DOUT + n0 + tx];
  __syncthreads();
#pragma unroll
  for (int i = 0; i < 32; i += 8)
    Out[(size_t)(n0 + ty + i) * DIN + k0 + tx] = f2bf(t[tx][ty + i]);
}

// ---------------- bf16 MFMA GEMM core (m97 structure) -----------------------

#define BKC 32   // bf16 elements per K step

__device__ __forceinline__ void stage_tile(
    const unsigned short* __restrict__ g, int row0, int k0,
    unsigned short* lds, int tid)
{
#pragma unroll
  for (int it = 0; it < 2; ++it) {
    int s = it * 256 + tid;              // chunk id 0..511 (16B chunks)
    int row = s >> 2, sc = s & 3;
    int gc = sc ^ ((row >> 1) & 3);      // swizzled source chunk
    const unsigned short* gsrc = g + (size_t)(row0 + row) * 768 + k0 + gc * 8;
    unsigned short* dst = lds + (size_t)(it * 256 + (tid & ~63)) * 8; // wave-uniform
    __builtin_amdgcn_global_load_lds(
        (const __attribute__((address_space(1))) void*)gsrc,
        (__attribute__((address_space(3))) void*)dst, 16, 0, 0);
  }
}

__device__ __forceinline__ void gemm_core(
    const unsigned short* __restrict__ A, const unsigned short* __restrict__ Bt,
    int m0, int n0, unsigned short* As, unsigned short* Bs,
    f32x4 acc[4][4], int tid)
{
  const int lane = tid & 63;
  const int col_l = lane & 15, quad = lane >> 4;
  const int w = tid >> 6;
  const int wm = (w & 1) * 64, wn = (w >> 1) * 64;
  for (int k0 = 0; k0 < 768; k0 += BKC) {
    __syncthreads();
    stage_tile(A, m0, k0, As, tid);
    stage_tile(Bt, n0, k0, Bs, tid);
    __syncthreads();
    s16x8 af[4], bf[4];
#pragma unroll
    for (int t = 0; t < 4; ++t) {
      int ar = wm + t * 16 + col_l;
      af[t] = *(const s16x8*)&As[ar * 32 + (quad ^ ((ar >> 1) & 3)) * 8];
      int br = wn + t * 16 + col_l;
      bf[t] = *(const s16x8*)&Bs[br * 32 + (quad ^ ((br >> 1) & 3)) * 8];
    }
#pragma unroll
    for (int mt = 0; mt < 4; ++mt)
#pragma unroll
      for (int nt = 0; nt < 4; ++nt)
        acc[mt][nt] = __builtin_amdgcn_mfma_f32_16x16x32_bf16(
            af[mt], bf[nt], acc[mt][nt], 0, 0, 0);
  }
}

// X@W -> Q/K/V bf16 [B,H,S,DH]; Q pre-scaled by 1/8
__global__ __launch_bounds__(256) void proj_mfma(
    const unsigned short* __restrict__ Xb, const unsigned short* __restrict__ Wt,
    unsigned short* __restrict__ Qo, unsigned short* __restrict__ Ko,
    unsigned short* __restrict__ Vo)
{
  __shared__ unsigned short As[128 * 32];
  __shared__ unsigned short Bs[128 * 32];
  const int tid = threadIdx.x;
  const int m0 = blockIdx.y * 128, n0 = blockIdx.x * 128;
  const int z = blockIdx.z;
  const unsigned short* Bw = Wt + (size_t)z * DOUT * DIN;
  unsigned short* Out = z == 0 ? Qo : z == 1 ? Ko : Vo;
  const float scale = z == 0 ? 0.125f : 1.0f;

  f32x4 acc[4][4] = {};
  gemm_core(Xb, Bw, m0, n0, As, Bs, acc, tid);

  const int lane = tid & 63, w = tid >> 6;
  const int col_l = lane & 15, quad = lane >> 4;
  const int wm = (w & 1) * 64, wn = (w >> 1) * 64;
#pragma unroll
  for (int mt = 0; mt < 4; ++mt)
#pragma unroll
    for (int nt = 0; nt < 4; ++nt) {
      int n = n0 + wn + nt * 16 + col_l;
      int h = n >> 6, d = n & 63;
#pragma unroll
      for (int r = 0; r < 4; ++r) {
        int m = m0 + wm + mt * 16 + quad * 4 + r;
        int b = m >> 11, s = m & (S_ - 1);
        Out[(((size_t)(b * H_ + h)) * S_ + s) * DH_ + d] = f2bf(acc[mt][nt][r] * scale);
      }
    }
}

// CTX@Wo + bo -> out fp32 [M, DOUT]
__global__ __launch_bounds__(256) void out_mfma(
    const unsigned short* __restrict__ Cb, const unsigned short* __restrict__ Wt,
    const float* __restrict__ bo, float* __restrict__ Out)
{
  __shared__ unsigned short As[128 * 32];
  __shared__ unsigned short Bs[128 * 32];
  const int tid = threadIdx.x;
  const int m0 = blockIdx.y * 128, n0 = blockIdx.x * 128;

  f32x4 acc[4][4] = {};
  gemm_core(Cb, Wt, m0, n0, As, Bs, acc, tid);

  const int lane = tid & 63, w = tid >> 6;
  const int col_l = lane & 15, quad = lane >> 4;
  const int wm = (w & 1) * 64, wn = (w >> 1) * 64;
#pragma unroll
  for (int mt = 0; mt < 4; ++mt)
#pragma unroll
    for (int nt = 0; nt < 4; ++nt) {
      int n = n0 + wn + nt * 16 + col_l;
      float bias = bo[n];
#pragma unroll
      for (int r = 0; r < 4; ++r) {
        int m = m0 + wm + mt * 16 + quad * 4 + r;
        Out[(size_t)m * DOUT + n] = acc[mt][nt][r] + bias;
      }
    }
}

// ---------------- MFMA flash attention, v2 ---------------------------------
// Paired q-tiles (p, 31-p): uniform 33 tile-works per block, K/V staging and
// K fragments shared by both. S^T orientation (A=K, B=Q): softmax stats are
// per-lane (query = lane&15), P stores are packed b64. Double-buffered K/V
// LDS, global loads for t+1 issued after the sync (latency hidden).

#define PSTR 72

union BF2 { __hip_bfloat162 v; unsigned u; };

__device__ __forceinline__ void attn_tile(
    const s16x8 kf[4][2], s16x8 aq0, s16x8 aq1,
    unsigned short* __restrict__ PsW, const unsigned short* __restrict__ VtB,
    f32x4 oacc[4], float& mrun, float& lrun,
    bool domask, int col_l, int quad, int w)
{
  f32x4 sc[4];
#pragma unroll
  for (int nc = 0; nc < 4; ++nc) {
    f32x4 a = {};
    a = __builtin_amdgcn_mfma_f32_16x16x32_bf16(kf[nc][0], aq0, a, 0, 0, 0);
    a = __builtin_amdgcn_mfma_f32_16x16x32_bf16(kf[nc][1], aq1, a, 0, 0, 0);
    sc[nc] = a;   // sc[nc][r] = S^T[key = nc*16+quad*4+r][query = col_l]
  }
  if (domask) {
    const int qrel = w * 16 + col_l;
#pragma unroll
    for (int nc = 0; nc < 4; ++nc)
#pragma unroll
      for (int r = 0; r < 4; ++r)
        if (nc * 16 + quad * 4 + r > qrel) sc[nc][r] = -INFINITY;
  }
  // row (query) max: 16 in-register + 2 shuffles (replicated across quads)
  float mloc = -INFINITY;
#pragma unroll
  for (int nc = 0; nc < 4; ++nc) {
    float m01 = fmaxf(sc[nc][0], sc[nc][1]);
    float m23 = fmaxf(sc[nc][2], sc[nc][3]);
    mloc = fmaxf(mloc, fmaxf(m01, m23));
  }
  mloc = fmaxf(mloc, __shfl_xor(mloc, 16));
  mloc = fmaxf(mloc, __shfl_xor(mloc, 32));
  float mnew = fmaxf(mrun, mloc);
  float alpha = __expf(mrun - mnew);   // first tile: exp(-inf)=0
  float ps = 0.f;
  uint2 pw[4];
#pragma unroll
  for (int nc = 0; nc < 4; ++nc) {
    float p0 = __expf(sc[nc][0] - mnew);
    float p1 = __expf(sc[nc][1] - mnew);
    float p2 = __expf(sc[nc][2] - mnew);
    float p3 = __expf(sc[nc][3] - mnew);
    ps += (p0 + p1) + (p2 + p3);
    BF2 lo, hi;
    lo.v = __float22bfloat162_rn(make_float2(p0, p1));
    hi.v = __float22bfloat162_rn(make_float2(p2, p3));
    pw[nc].x = lo.u; pw[nc].y = hi.u;
  }
  ps += __shfl_xor(ps, 16);
  ps += __shfl_xor(ps, 32);
  lrun = lrun * alpha + ps;
  mrun = mnew;
  // P^T -> LDS (packed 8B writes), layout Ps[query][key]
#pragma unroll
  for (int nc = 0; nc < 4; ++nc)
    *(uint2*)&PsW[col_l * PSTR + nc * 16 + quad * 4] = pw[nc];
  // rescale O (rows = quad*4+r): fetch alpha for those queries
  float a_r[4];
#pragma unroll
  for (int r = 0; r < 4; ++r) a_r[r] = __shfl(alpha, quad * 4 + r);
#pragma unroll
  for (int dc = 0; dc < 4; ++dc)
#pragma unroll
    for (int r = 0; r < 4; ++r) oacc[dc][r] *= a_r[r];
  // PV: A = P (A-layout from Ps), B = V^T (from Vt)
  s16x8 ap0 = *(const s16x8*)&PsW[col_l * PSTR + quad * 8];
  s16x8 ap1 = *(const s16x8*)&PsW[col_l * PSTR + 32 + quad * 8];
#pragma unroll
  for (int dc = 0; dc < 4; ++dc) {
    s16x8 bv0 = *(const s16x8*)&VtB[(dc * 16 + col_l) * PSTR + quad * 8];
    s16x8 bv1 = *(const s16x8*)&VtB[(dc * 16 + col_l) * PSTR + 32 + quad * 8];
    oacc[dc] = __builtin_amdgcn_mfma_f32_16x16x32_bf16(ap0, bv0, oacc[dc], 0, 0, 0);
    oacc[dc] = __builtin_amdgcn_mfma_f32_16x16x32_bf16(ap1, bv1, oacc[dc], 0, 0, 0);
  }
}

__global__ __launch_bounds__(256, 3) void attn_mfma(
    const unsigned short* __restrict__ Q, const unsigned short* __restrict__ K,
    const unsigned short* __restrict__ V, unsigned short* __restrict__ CTX)
{
  __shared__ unsigned short Vt[2][64 * PSTR];   // Vt[d][key], transposed
  __shared__ unsigned short Ks[2][64 * PSTR];   // Ks[key][d], natural
  __shared__ unsigned short Ps[4][16 * PSTR];   // per-wave P scratch

  const int tid = threadIdx.x;
  const int lane = tid & 63;
  const int w = tid >> 6;
  const int col_l = lane & 15;
  const int quad = lane >> 4;
  const int vkey = lane;
  const int b = blockIdx.z, h = blockIdx.y;
  const int p = blockIdx.x;                      // pair index 0..15
  const int q0A = p << 6, q0B = (31 - p) << 6;   // two q-tiles
  const int ntiles = 32 - p;                     // B's tile count (A's = p+1)
  const size_t bh = (size_t)(b * H_ + h);
  const unsigned short* Qb = Q + bh * S_ * DH_;
  const unsigned short* Kb = K + bh * S_ * DH_;
  const unsigned short* Vb = V + bh * S_ * DH_;
  unsigned short* PsW = &Ps[w][0];

  // Q fragments (B-operand layout), both q-tiles; scale folded at projection
  const int qwA = q0A + (w << 4), qwB = q0B + (w << 4);
  s16x8 aqA0 = *(const s16x8*)&Qb[(size_t)(qwA + col_l) * DH_ + quad * 8];
  s16x8 aqA1 = *(const s16x8*)&Qb[(size_t)(qwA + col_l) * DH_ + 32 + quad * 8];
  s16x8 aqB0 = *(const s16x8*)&Qb[(size_t)(qwB + col_l) * DH_ + quad * 8];
  s16x8 aqB1 = *(const s16x8*)&Qb[(size_t)(qwB + col_l) * DH_ + 32 + quad * 8];

  f32x4 oA[4] = {}, oB[4] = {};
  float mA = -INFINITY, lA = 0.f, mB = -INFINITY, lB = 0.f;

  // preload tile 0 into regs (each thread: key=lane, d-chunks w and w+4)
  s16x8 vvn0 = *(const s16x8*)&Vb[(size_t)vkey * DH_ + w * 8];
  s16x8 vvn1 = *(const s16x8*)&Vb[(size_t)vkey * DH_ + (w + 4) * 8];
  s16x8 kvn0 = *(const s16x8*)&Kb[(size_t)vkey * DH_ + w * 8];
  s16x8 kvn1 = *(const s16x8*)&Kb[(size_t)vkey * DH_ + (w + 4) * 8];

  for (int t = 0; t < ntiles; ++t) {
    const int buf = t & 1;
    unsigned short* VtB = &Vt[buf][0];
    unsigned short* KsB = &Ks[buf][0];
    // stage regs -> LDS (waits vmcnt on the prefetch automatically)
    *(s16x8*)&KsB[vkey * PSTR + w * 8] = kvn0;
    *(s16x8*)&KsB[vkey * PSTR + (w + 4) * 8] = kvn1;
#pragma unroll
    for (int j = 0; j < 8; ++j) {
      VtB[(w * 8 + j) * PSTR + vkey] = (unsigned short)vvn0[j];
      VtB[((w + 4) * 8 + j) * PSTR + vkey] = (unsigned short)vvn1[j];
    }
    __syncthreads();
    // prefetch tile t+1 (clamped; issued after sync so latency overlaps compute)
    {
      const int jn = (t + 1 < ntiles ? t + 1 : t) << 6;
      vvn0 = *(const s16x8*)&Vb[(size_t)(jn + vkey) * DH_ + w * 8];
      vvn1 = *(const s16x8*)&Vb[(size_t)(jn + vkey) * DH_ + (w + 4) * 8];
      kvn0 = *(const s16x8*)&Kb[(size_t)(jn + vkey) * DH_ + w * 8];
      kvn1 = *(const s16x8*)&Kb[(size_t)(jn + vkey) * DH_ + (w + 4) * 8];
    }
    // K fragments (A-operand layout), shared by both q-tiles
    s16x8 kf[4][2];
#pragma unroll
    for (int nc = 0; nc < 4; ++nc) {
      kf[nc][0] = *(const s16x8*)&KsB[(nc * 16 + col_l) * PSTR + quad * 8];
      kf[nc][1] = *(const s16x8*)&KsB[(nc * 16 + col_l) * PSTR + 32 + quad * 8];
    }
    if (t <= p)
      attn_tile(kf, aqA0, aqA1, PsW, VtB, oA, mA, lA, t == p, col_l, quad, w);
    attn_tile(kf, aqB0, aqB1, PsW, VtB, oB, mB, lB, t == ntiles - 1, col_l, quad, w);
  }

  // epilogue: CTX[b*S+q][h*64+d] = O/l  (O rows = quad*4+r, d = dc*16+col_l)
  float liA[4], liB[4];
#pragma unroll
  for (int r = 0; r < 4; ++r) {
    liA[r] = 1.0f / __shfl(lA, quad * 4 + r);
    liB[r] = 1.0f / __shfl(lB, quad * 4 + r);
  }
#pragma unroll
  for (int dc = 0; dc < 4; ++dc)
#pragma unroll
    for (int r = 0; r < 4; ++r) {
      CTX[((size_t)(b * S_ + qwA + quad * 4 + r)) * DOUT + h * DH_ + dc * 16 + col_l]
          = f2bf(oA[dc][r] * liA[r]);
      CTX[((size_t)(b * S_ + qwB + quad * 4 + r)) * DOUT + h * DH_ + dc * 16 + col_l]
          = f2bf(oB[dc][r] * liB[r]);
    }
}

// ---------------- launcher ----------------

extern "C" void kernel_launch(void* const* d_in, const int* in_sizes, int n_in,
                              void* d_out, int out_size, void* d_ws, size_t ws_size,
                              hipStream_t stream) {
  const float* X  = (const float*)d_in[0];
  // d_in[1] is the causal mask (bool) — exactly triu(k=1), hardcoded in attn.
  const float* Wq = (const float*)d_in[2];
  const float* Wk = (const float*)d_in[3];
  const float* Wv = (const float*)d_in[4];
  const float* Wo = (const float*)d_in[5];
  const float* bo = (const float*)d_in[6];
  float* out = (float*)d_out;

  unsigned short* Xb = (unsigned short*)d_ws;            // [M, DIN] bf16
  unsigned short* Wt = Xb + (size_t)M_ * DIN;            // [4][DOUT][DIN] bf16 (n-major)
  unsigned short* Qb = Wt + (size_t)4 * DOUT * DIN;      // [B,H,S,DH] bf16
  unsigned short* Kb = Qb + (size_t)M_ * DOUT;
  unsigned short* Vb = Kb + (size_t)M_ * DOUT;
  unsigned short* Cb = Vb + (size_t)M_ * DOUT;           // [M, DOUT] bf16

  cast_x<<<dim3((M_ * DIN) / (256 * 8)), 256, 0, stream>>>(X, Xb);
  tcast_w<<<dim3(DOUT / 32, DIN / 32, 4), 256, 0, stream>>>(Wq, Wk, Wv, Wo, Wt);
  proj_mfma<<<dim3(DOUT / 128, M_ / 128, 3), 256, 0, stream>>>(Xb, Wt, Qb, Kb, Vb);
  attn_mfma<<<dim3(16, H_, B_), 256, 0, stream>>>(Qb, Kb, Vb, Cb);
  out_mfma<<<dim3(DOUT / 128, M_ / 128), 256, 0, stream>>>(
      Cb, Wt + (size_t)3 * DOUT * DIN, bo, out);
}